// Round 19
// baseline (8128.673 us; speedup 1.0000x reference)
//
#include <hip/hip_runtime.h>

// ---------------------------------------------------------------------------
// OmniAnomaly forward, round 19: r18 (L2-resident weights, 7.89ms) with
// targeted 8-flag producer-consumer waits instead of 128-wide barriers.
// Every phase input is produced by exactly 8 WGs (same-slab across XCD
// groups, or the 8 flow-WGs of a slab) -> poll just those. Slabs decouple.
// FB path (ws<400MB): r18's full barriers, unchanged.
// B=256, W=128, IN=128, H=1024, Z=128, D=1024, OUT=128, K=3 flows
// ---------------------------------------------------------------------------

typedef __bf16 bf16;
typedef __bf16 bf16x8 __attribute__((ext_vector_type(8)));
typedef float  f32x4  __attribute__((ext_vector_type(4)));
typedef unsigned u32;

static constexpr int CB   = 256;
static constexpr int CW   = 128;
static constexpr int CIN  = 128;
static constexpr int CH   = 1024;
static constexpr int CZ   = 128;
static constexpr int CD   = 1024;
static constexpr int COUT = 128;

static constexpr int APITCH     = 1160;                      // 1152 + 8 pad
static constexpr int ABUF_BYTES = 16 * APITCH * 2;           // 37120
static constexpr int REDN       = 8 * 16 * 17;
static constexpr int RED2_BYTES = 2 * REDN * 4;              // 17408
static constexpr int FLOW_BYTES = (2 * CZ + 2 * 2 * CZ) * 4; // 3072
static constexpr int SMEM_BYTES = ABUF_BYTES + RED2_BYTES + FLOW_BYTES; // 57600

#define DEV static __device__ __forceinline__

DEV float sigmoidf_(float x) { return 1.0f / (1.0f + expf(-x)); }
DEV float softplusf_(float x) { return x > 20.0f ? x : log1pf(expf(x)); }
DEV bf16x8 ldfrag(const bf16* p) { return *reinterpret_cast<const bf16x8*>(p); }

#define MFMA(a, b, c) __builtin_amdgcn_mfma_f32_16x16x32_bf16((a), (b), (c), 0, 0, 0)

// device-coherent (sc0 sc1) accesses
DEV bf16x8 ldd16(const bf16* p) {
    bf16x8 v;
    asm volatile("global_load_dwordx4 %0, %1, off sc0 sc1\n\ts_waitcnt vmcnt(0)"
                 : "=v"(v) : "v"(p) : "memory");
    return v;
}
DEV bf16x8 ldd16_nw(const bf16* p) {
    bf16x8 v;
    asm volatile("global_load_dwordx4 %0, %1, off sc0 sc1"
                 : "=v"(v) : "v"(p) : "memory");
    return v;
}
DEV u32 ldd4(const void* p) {
    u32 v;
    asm volatile("global_load_dword %0, %1, off sc0 sc1\n\ts_waitcnt vmcnt(0)"
                 : "=v"(v) : "v"(p) : "memory");
    return v;
}
DEV void std4(void* p, u32 v) {
    asm volatile("global_store_dword %0, %1, off sc0 sc1" :: "v"(p), "v"(v) : "memory");
}
DEV void vm_wait0() {
    asm volatile("s_waitcnt vmcnt(0)" ::: "memory");
    __builtin_amdgcn_sched_barrier(0);
}
DEV u32 pk2(float a, float b) {
    union { bf16 h[2]; u32 u; } r;
    r.h[0] = (bf16)a; r.h[1] = (bf16)b;
    return r.u;
}

struct Prm {
    const float *eps_q, *eps_p;
    const float *bih_q, *bhh_q, *bd_q, *bmu_q, *bsig_q;
    const float *Wp, *bp, *up, *Wlg, *blg;
    const float *bih_p, *bhh_p, *bd_p, *bmu_p, *bsig_p;
    const bf16 *x_b, *Wih_qb, *Whh_qb, *Wd_qb, *Wmu_qb, *Wsg_qb;
    const bf16 *Wih_pb, *Whh_pb, *Wd_pb, *Wmu_pb, *Wsg_pb;
    float *e_f0, *e_f1, *d_f0, *d_f1;
    bf16 *e_h, *d_h;        // [(BIG?CW+1:2)][CB][CH]
    bf16 *dvec_h, *ddvec_h; // [(BIG?CW:1)][CB][CD]
    float *ztmp_h;          // [(BIG?CW:1)][CB][CZ]
    bf16 *zflow_h;          // [(BIG?CW+1:2)][CB][CZ]
    bf16 *ztlg_h;           // [(BIG?CW:2)][CB][CZ]
    u32 *qbar, *pbar, *zbar, *pdone;          // FB full barriers
    u32 *qg, *ql, *qt, *qf, *pg, *pl;         // BIG targeted flags
    float *out_o, *out_mu, *out_lv;
};

// ---- FB: 128-WG per-side barrier (r8-proven) ----
DEV void gbar128(u32* flg, int lwg, u32 k)
{
    asm volatile("s_waitcnt vmcnt(0)" ::: "memory");
    __syncthreads();
    if (threadIdx.x == 0)
        __hip_atomic_store(&flg[lwg * 16], k, __ATOMIC_RELAXED, __HIP_MEMORY_SCOPE_AGENT);
    if (threadIdx.x < 128) {
        while (__hip_atomic_load(&flg[threadIdx.x * 16], __ATOMIC_RELAXED,
                                 __HIP_MEMORY_SCOPE_AGENT) < k)
            __builtin_amdgcn_s_sleep(1);
    }
    __syncthreads();
}

// ---- BIG: targeted post / 8-flag waits ----
DEV void post_flag(u32* f, int lwg, u32 k)
{
    asm volatile("s_waitcnt vmcnt(0)" ::: "memory");   // drain this wave's stores
    __syncthreads();                                   // whole WG drained
    if (threadIdx.x == 0)
        __hip_atomic_store(&f[lwg * 16], k, __ATOMIC_RELAXED, __HIP_MEMORY_SCOPE_AGENT);
}
// producers = same slab across 4 XCD groups x 2 halves
DEV void wait_slab8(const u32* f, int slab, u32 k)
{
    if (threadIdx.x < 8) {
        const int idx = (threadIdx.x >> 1) * 32 + slab * 2 + (threadIdx.x & 1);
        while (__hip_atomic_load(&f[idx * 16], __ATOMIC_RELAXED,
                                 __HIP_MEMORY_SCOPE_AGENT) < k)
            __builtin_amdgcn_s_sleep(1);
    }
    __syncthreads();
}
// producers = 8 contiguous flow-WGs [base, base+8)
DEV void wait_rng8(const u32* f, int base, u32 k)
{
    if ((int)k > 0 && threadIdx.x < 8) {
        while (__hip_atomic_load(&f[(base + threadIdx.x) * 16], __ATOMIC_RELAXED,
                                 __HIP_MEMORY_SCOPE_AGENT) < k)
            __builtin_amdgcn_s_sleep(1);
    }
    __syncthreads();
}

// ---------------------------------------------------------------------------
__global__ void k_cvt(const float* __restrict__ src, bf16* __restrict__ dst, int n)
{
    int i = (blockIdx.x * blockDim.x + threadIdx.x) * 4;
    if (i < n) {
        float4 v = *reinterpret_cast<const float4*>(src + i);
        *reinterpret_cast<u32*>(dst + i)     = pk2(v.x, v.y);
        *reinterpret_cast<u32*>(dst + i + 2) = pk2(v.z, v.w);
    }
}

// ---------------------------------------------------------------------------
template <bool BIG, int HM>
DEV void stage_act(bf16* abuf, int tid, int r0,
                   const bf16* head, long hs, int K1,
                   const bf16* body, long bs)
{
    if constexpr (BIG) {
        for (int j = 0; j < 4; ++j) {
            const int idx = tid + j * 512;
            const int row = idx >> 7;
            const int k = (idx & 127) * 8;
            *reinterpret_cast<bf16x8*>(abuf + (long)row * APITCH + K1 + k) =
                ldfrag(body + (long)(r0 + row) * bs + k);
        }
    } else {
        bf16x8 v[4];
        long dst[4];
#pragma unroll
        for (int j = 0; j < 4; ++j) {
            const int idx = tid + j * 512;
            const int row = idx >> 7;
            const int k = (idx & 127) * 8;
            v[j] = ldd16_nw(body + (long)(r0 + row) * bs + k);
            dst[j] = (long)row * APITCH + K1 + k;
        }
        vm_wait0();
#pragma unroll
        for (int j = 0; j < 4; ++j)
            *reinterpret_cast<bf16x8*>(abuf + dst[j]) = v[j];
    }
    if (K1 > 0) {
        const int HC = K1 >> 3;
        for (int idx = tid; idx < 16 * HC; idx += 512) {
            const int row = idx / HC;
            const int k = (idx - row * HC) * 8;
            const bf16* s = head + (long)(r0 + row) * hs + k;
            bf16x8 hv;
            if constexpr (HM == 0) hv = ldfrag(s);
            else                   hv = BIG ? ldfrag(s) : ldd16(s);
            *reinterpret_cast<bf16x8*>(abuf + (long)row * APITCH + k) = hv;
        }
    }
    __syncthreads();
}

// ---------------------------------------------------------------------------
DEV void gru_compute(const bf16* abuf, int r0, int n0, int lane, int wave,
                     const bf16* __restrict__ Wih, const bf16* __restrict__ Whh,
                     const float* __restrict__ bih, const float* __restrict__ bhh,
                     const float* __restrict__ Efin,
                     float* __restrict__ Efo, bf16* __restrict__ Ebo)
{
    const int lr = lane & 15, lkE = (lane >> 4) * 8;
    const int c = n0 + wave * 16 + lr;
    const bf16* arow = abuf + (long)lr * APITCH;

    f32x4 acc[4] = {};
    {
        bf16x8 wv[4][3];
#pragma unroll
        for (int j = 0; j < 4; ++j)
#pragma unroll
            for (int g = 0; g < 3; ++g)
                wv[j][g] = ldfrag(Wih + ((long)g * CH + c) * CIN + j * 32 + lkE);
#pragma unroll
        for (int j = 0; j < 4; ++j) {
            bf16x8 a = *reinterpret_cast<const bf16x8*>(arow + j * 32 + lkE);
            acc[0] = MFMA(a, wv[j][0], acc[0]);
            acc[1] = MFMA(a, wv[j][1], acc[1]);
            acc[2] = MFMA(a, wv[j][2], acc[2]);
        }
    }
    {
        const bf16* wp0 = Whh + ((long)0 * CH + c) * CH + lkE;
        const bf16* wp1 = Whh + ((long)1 * CH + c) * CH + lkE;
        const bf16* wp2 = Whh + ((long)2 * CH + c) * CH + lkE;
        bf16x8 wv[4][3];
#pragma unroll
        for (int j = 0; j < 4; ++j) {
            wv[j][0] = ldfrag(wp0 + j * 32);
            wv[j][1] = ldfrag(wp1 + j * 32);
            wv[j][2] = ldfrag(wp2 + j * 32);
        }
#pragma unroll
        for (int kb = 0; kb < 32; ++kb) {
            const int sl = kb & 3;
            bf16x8 a = *reinterpret_cast<const bf16x8*>(arow + CIN + kb * 32 + lkE);
            acc[0] = MFMA(a, wv[sl][0], acc[0]);
            acc[1] = MFMA(a, wv[sl][1], acc[1]);
            acc[3] = MFMA(a, wv[sl][2], acc[3]);
            if (kb < 28) {
                wv[sl][0] = ldfrag(wp0 + (kb + 4) * 32);
                wv[sl][1] = ldfrag(wp1 + (kb + 4) * 32);
                wv[sl][2] = ldfrag(wp2 + (kb + 4) * 32);
            }
        }
    }

    const float b0r = bih[c] + bhh[c];
    const float b0z = bih[CH + c] + bhh[CH + c];
    const float bin = bih[2 * CH + c];
    const float bhn = bhh[2 * CH + c];
    const int rbase = r0 + (lane >> 4) * 4;
#pragma unroll
    for (int i = 0; i < 4; ++i) {
        const int row = rbase + i;
        float r = sigmoidf_(acc[0][i] + b0r);
        float u = sigmoidf_(acc[1][i] + b0z);
        float n = tanhf(acc[2][i] + bin + r * (acc[3][i] + bhn));
        float en = (1.0f - u) * n + u * Efin[(long)row * CH + c];
        Efo[(long)row * CH + c] = en;
        float vB = __shfl_xor(en, 1);
        if (!(lane & 1))
            std4(Ebo + (long)row * CH + c, pk2(en, vB));
    }
}

// ---------------------------------------------------------------------------
DEV void lin_compute(const bf16* abuf, int r0, int n0, int lane, int wave, int Ktot,
                     const bf16* __restrict__ W,
                     const float* __restrict__ bias, bf16* __restrict__ Out)
{
    const int lr = lane & 15, lkE = (lane >> 4) * 8;
    const int c = n0 + wave * 16 + lr;
    const bf16* arow = abuf + (long)lr * APITCH;
    const bf16* wrow = W + (long)c * Ktot;
    const int kofs = Ktot - CH;

    f32x4 acc = {};
    {
        const bf16* wp = wrow + kofs + lkE;
        bf16x8 wv[8];
#pragma unroll
        for (int j = 0; j < 8; ++j) wv[j] = ldfrag(wp + j * 32);
#pragma unroll
        for (int kb = 0; kb < 32; ++kb) {
            const int sl = kb & 7;
            bf16x8 a = *reinterpret_cast<const bf16x8*>(arow + kofs + kb * 32 + lkE);
            acc = MFMA(a, wv[sl], acc);
            if (kb < 24) wv[sl] = ldfrag(wp + (kb + 8) * 32);
        }
    }
    if (Ktot > CH) {
        bf16x8 wv[4];
#pragma unroll
        for (int j = 0; j < 4; ++j) wv[j] = ldfrag(wrow + j * 32 + lkE);
#pragma unroll
        for (int j = 0; j < 4; ++j) {
            bf16x8 a = *reinterpret_cast<const bf16x8*>(arow + j * 32 + lkE);
            acc = MFMA(a, wv[j], acc);
        }
    }

    const float bb = bias[c];
    const int rbase = r0 + (lane >> 4) * 4;
#pragma unroll
    for (int i = 0; i < 4; ++i) {
        float v = acc[i] + bb;
        float vB = __shfl_xor(v, 1);
        if (!(lane & 1))
            std4(Out + (long)(rbase + i) * CD + c, pk2(v, vB));
    }
}

// ---------------------------------------------------------------------------
template <bool BIG, int MODE>
DEV void phase_tail2(const Prm& p, int t, int mb, int nb, int tid,
                     int lane, int wave, float* Ra, float* Rs,
                     const bf16* __restrict__ A, float* __restrict__ ztmp,
                     const bf16* __restrict__ Wa, const bf16* __restrict__ Wb,
                     const float* __restrict__ ba, const float* __restrict__ bb)
{
    const int lr = lane & 15, lkE = (lane >> 4) * 8;
    f32x4 am = {}, as = {};
    const int k0 = wave * 128;
    bf16x8 av[4], bmv[4], bsv[4];
#pragma unroll
    for (int j = 0; j < 4; ++j) {
        const int k = k0 + j * 32;
        const bf16* ap = A + (long)(mb + lr) * CD + k + lkE;
        av[j]  = BIG ? ldfrag(ap) : ldd16_nw(ap);
        bmv[j] = ldfrag(Wa + (long)(nb + lr) * CD + k + lkE);
        bsv[j] = ldfrag(Wb + (long)(nb + lr) * CD + k + lkE);
    }
    if constexpr (!BIG) vm_wait0();
#pragma unroll
    for (int j = 0; j < 4; ++j) {
        am = MFMA(av[j], bmv[j], am);
        as = MFMA(av[j], bsv[j], as);
    }
    __syncthreads();
#pragma unroll
    for (int i = 0; i < 4; ++i) {
        Ra[(wave * 16 + (lane >> 4) * 4 + i) * 17 + lr] = am[i];
        Rs[(wave * 16 + (lane >> 4) * 4 + i) * 17 + lr] = as[i];
    }
    __syncthreads();
    if (tid < 256) {
        const int trow = tid >> 4, tcol = tid & 15;
        float vm = 0.f, vs = 0.f;
#pragma unroll
        for (int w = 0; w < 8; ++w) {
            vm += Ra[(w * 16 + trow) * 17 + tcol];
            vs += Rs[(w * 16 + trow) * 17 + tcol];
        }
        const int row = mb + trow, col = nb + tcol;
        if constexpr (MODE == 0) {
            float mu = vm + ba[col];
            float lv = softplusf_(vs + bb[col]);
            float e  = p.eps_q[(long)row * CW * CZ + (long)t * CZ + col];
            float z  = mu + expf(0.5f * lv) * e;
            p.out_mu[(long)row * CW * CZ + (long)t * CZ + col] = mu;
            p.out_lv[(long)row * CW * CZ + (long)t * CZ + col] = lv;
            std4(ztmp + (long)row * CZ + col, __float_as_uint(z));
        } else {
            float m  = vm + ba[col];
            float sg = softplusf_(vs + bb[col]);
            float e  = p.eps_p[(long)row * CW * COUT + (long)t * COUT + col];
            p.out_o[(long)row * CW * COUT + (long)t * COUT + col] = m + sg * e;
        }
    }
}

// ---------------------------------------------------------------------------
template <bool BIG>
DEV void phase_flows2(const Prm& p, int rowbase, int tid, int t, float* zl, float* ps,
                      const float* __restrict__ ztmp,
                      bf16* __restrict__ ztlg, bf16* __restrict__ zflow_next)
{
    const int rg = tid >> 8;
    const int sub = tid & 255;
    const int c = sub & 127, half = sub >> 7;
    const int row = rowbase + rg;
    float* zrow = zl + rg * CZ;
    float* pall = ps + rg * 2 * CZ;

    if (half == 0)
        zrow[c] = BIG ? ztmp[(long)row * CZ + c]
                      : __uint_as_float(ldd4(ztmp + (long)row * CZ + c));
    __syncthreads();

#pragma unroll 1
    for (int kf = 0; kf < 3; ++kf) {
        const float* wr = p.Wp + ((long)kf * CZ + c) * CZ + half * 64;
        const float* zh = zrow + half * 64;
        float s = 0.f;
#pragma unroll
        for (int j = 0; j < 64; j += 4) {
            float4 w = *reinterpret_cast<const float4*>(wr + j);
            s += zh[j] * w.x + zh[j + 1] * w.y + zh[j + 2] * w.z + zh[j + 3] * w.w;
        }
        pall[half * CZ + c] = s;
        __syncthreads();
        if (half == 0) {
            float sf = pall[c] + pall[CZ + c] + p.bp[kf * CZ + c];
            zrow[c] += p.up[kf] * tanhf(sf);
        }
        __syncthreads();
    }
    {
        const float* wr = p.Wlg + (long)c * CZ + half * 64;
        const float* zh = zrow + half * 64;
        float s = 0.f;
#pragma unroll
        for (int j = 0; j < 64; j += 4) {
            float4 w = *reinterpret_cast<const float4*>(wr + j);
            s += zh[j] * w.x + zh[j + 1] * w.y + zh[j + 2] * w.z + zh[j + 3] * w.w;
        }
        pall[half * CZ + c] = s;
        __syncthreads();
        if (half == 0) {
            float zt = pall[c] + pall[CZ + c] + p.blg[c];
            float ztB = __shfl_xor(zt, 1);
            if (!(c & 1)) {
                std4(ztlg + (long)row * CZ + c, pk2(zt, ztB));
                std4(zflow_next + (long)row * CZ + c, pk2(zrow[c], zrow[c + 1]));
            }
        }
    }
}

// ---------------------------------------------------------------------------
template <bool BIG>
DEV void run_q(const Prm& p, int lwg, int tid,
               bf16* abuf, float* Ra, float* Rs, float* ZLp, float* PSp)
{
    const int lane = tid & 63, wave = tid >> 6;
    const int g = lwg >> 5, m = lwg & 31;
    const int slab = m >> 1;
    const int r0 = slab * 16;
    const int n0 = g * 256 + (m & 1) * 128;
    const int nt = g * 32 + (m & 1) * 16;
    const size_t SH = (size_t)CB * CH, SD = (size_t)CB * CD, SZ = (size_t)CB * CZ;
    u32 bk = 0;
#pragma unroll 1
    for (int t = 0; t < CW; ++t) {
        const int eIn  = BIG ? t : (t & 1);
        const int eOut = BIG ? (t + 1) : ((t + 1) & 1);
        const int dT   = BIG ? t : 0;
        const int zT   = BIG ? t : (t & 1);
        const float* ef_i = (t & 1) ? p.e_f1 : p.e_f0;
        float*       ef_o = (t & 1) ? p.e_f0 : p.e_f1;

        // Q1: GRU (e_h[t] read covered by prior iteration's waits)
        stage_act<BIG, 0>(abuf, tid, r0, p.x_b + (long)t * CIN, (long)CW * CIN,
                          CIN, p.e_h + (size_t)eIn * SH, CH);
        gru_compute(abuf, r0, n0, lane, wave, p.Wih_qb, p.Whh_qb,
                    p.bih_q, p.bhh_q, ef_i, ef_o, p.e_h + (size_t)eOut * SH);
        if constexpr (BIG) post_flag(p.qg, lwg, (u32)(t + 1));
        else               gbar128(p.qbar, lwg, ++bk);

        // Q2: lin
        if constexpr (BIG) {
            wait_rng8(p.qf, slab * 8, (u32)t);      // zflow[t] (flows(t-1))
            wait_slab8(p.qg, slab, (u32)(t + 1));   // e_h[t+1]
        }
        stage_act<BIG, 1>(abuf, tid, r0, p.zflow_h + (size_t)eIn * SZ, CZ, CZ,
                          p.e_h + (size_t)eOut * SH, CH);
        lin_compute(abuf, r0, n0, lane, wave, CZ + CH, p.Wd_qb, p.bd_q,
                    p.dvec_h + (size_t)dT * SD);
        if constexpr (BIG) post_flag(p.ql, lwg, (u32)(t + 1));
        else               gbar128(p.qbar, lwg, ++bk);

        // Q3: heads + reparam
        if constexpr (BIG) wait_slab8(p.ql, slab, (u32)(t + 1));
        phase_tail2<BIG, 0>(p, t, r0, nt, tid, lane, wave, Ra, Rs,
                            p.dvec_h + (size_t)dT * SD, p.ztmp_h + (size_t)dT * SZ,
                            p.Wmu_qb, p.Wsg_qb, p.bmu_q, p.bsig_q);
        if constexpr (BIG) post_flag(p.qt, lwg, (u32)(t + 1));
        else               gbar128(p.qbar, lwg, ++bk);

        // Q4: flows
        if constexpr (BIG) {
            wait_slab8(p.qt, lwg >> 3, (u32)(t + 1));   // ztmp rows lwg*2..+2
        } else {
            if (t >= 2) {
                if (tid < 128) {
                    while ((int)__hip_atomic_load(&p.pdone[tid * 16], __ATOMIC_RELAXED,
                                                  __HIP_MEMORY_SCOPE_AGENT) < t - 1)
                        __builtin_amdgcn_s_sleep(2);
                }
                __syncthreads();
            }
        }
        phase_flows2<BIG>(p, lwg * 2, tid, t, ZLp, PSp,
                          p.ztmp_h + (size_t)dT * SZ,
                          p.ztlg_h + (size_t)zT * SZ,
                          p.zflow_h + (size_t)eOut * SZ);
        if constexpr (BIG) {
            post_flag(p.qf, lwg, (u32)(t + 1));
        } else {
            asm volatile("s_waitcnt vmcnt(0)" ::: "memory");
            __syncthreads();
            if (tid == 0)
                __hip_atomic_store(&p.zbar[lwg * 16], (u32)(t + 1),
                                   __ATOMIC_RELAXED, __HIP_MEMORY_SCOPE_AGENT);
            __syncthreads();
        }
    }
}

template <bool BIG>
DEV void run_p(const Prm& p, int lwg, int tid,
               bf16* abuf, float* Ra, float* Rs)
{
    const int lane = tid & 63, wave = tid >> 6;
    const int g = lwg >> 5, m = lwg & 31;
    const int slab = m >> 1;
    const int r0 = slab * 16;
    const int n0 = g * 256 + (m & 1) * 128;
    const int nt = g * 32 + (m & 1) * 16;
    const size_t SH = (size_t)CB * CH, SD = (size_t)CB * CD, SZ = (size_t)CB * CZ;
    u32 bk = 0;
#pragma unroll 1
    for (int t = 0; t < CW; ++t) {
        if constexpr (BIG) {
            wait_rng8(p.qf, slab * 8, (u32)(t + 1));    // ztlg[t]
        } else {
            if (tid < 128) {
                while (__hip_atomic_load(&p.zbar[tid * 16], __ATOMIC_RELAXED,
                                         __HIP_MEMORY_SCOPE_AGENT) < (u32)(t + 1))
                    __builtin_amdgcn_s_sleep(2);
            }
            __syncthreads();
        }

        const int sIn  = BIG ? t : (t & 1);
        const int sOut = BIG ? (t + 1) : ((t + 1) & 1);
        const int dT   = BIG ? t : 0;
        const int zT   = BIG ? t : (t & 1);
        const float* df_i = (t & 1) ? p.d_f1 : p.d_f0;
        float*       df_o = (t & 1) ? p.d_f0 : p.d_f1;

        // P1: GRU
        stage_act<BIG, 1>(abuf, tid, r0, p.ztlg_h + (size_t)zT * SZ, CZ, CZ,
                          p.d_h + (size_t)sIn * SH, CH);
        gru_compute(abuf, r0, n0, lane, wave, p.Wih_pb, p.Whh_pb,
                    p.bih_p, p.bhh_p, df_i, df_o, p.d_h + (size_t)sOut * SH);
        if constexpr (BIG) post_flag(p.pg, lwg, (u32)(t + 1));
        else {
            gbar128(p.pbar, lwg, ++bk);
            if (tid == 0)
                __hip_atomic_store(&p.pdone[lwg * 16], (u32)(t + 1),
                                   __ATOMIC_RELAXED, __HIP_MEMORY_SCOPE_AGENT);
        }

        // P2: lin
        if constexpr (BIG) wait_slab8(p.pg, slab, (u32)(t + 1));
        stage_act<BIG, 0>(abuf, tid, r0, nullptr, 0, 0,
                          p.d_h + (size_t)sOut * SH, CH);
        lin_compute(abuf, r0, n0, lane, wave, CH, p.Wd_pb, p.bd_p,
                    p.ddvec_h + (size_t)dT * SD);
        if constexpr (BIG) post_flag(p.pl, lwg, (u32)(t + 1));
        else               gbar128(p.pbar, lwg, ++bk);

        // P3: output head
        if constexpr (BIG) wait_slab8(p.pl, slab, (u32)(t + 1));
        phase_tail2<BIG, 1>(p, t, r0, nt, tid, lane, wave, Ra, Rs,
                            p.ddvec_h + (size_t)dT * SD, nullptr,
                            p.Wmu_pb, p.Wsg_pb, p.bmu_p, p.bsig_p);
    }
}

// ---------------------------------------------------------------------------
template <bool BIG>
__launch_bounds__(512)
__global__ void mega(Prm p)
{
    extern __shared__ char smem[];
    bf16*  abuf = (bf16*)smem;
    float* Ra   = (float*)(smem + ABUF_BYTES);
    float* Rs   = Ra + REDN;
    float* ZLp  = (float*)(smem + ABUF_BYTES + RED2_BYTES);
    float* PSp  = ZLp + 2 * CZ;

    const int wg = blockIdx.x, tid = threadIdx.x;
    const int gid = wg & 7, m = wg >> 3;          // m 0..31
    const bool isQ = gid < 4;
    const int lwg = (isQ ? gid : gid - 4) * 32 + m;

    if (isQ) run_q<BIG>(p, lwg, tid, abuf, Ra, Rs, ZLp, PSp);
    else     run_p<BIG>(p, lwg, tid, abuf, Ra, Rs);
}

// ---------------------------------------------------------------------------
// Host driver
// ---------------------------------------------------------------------------
extern "C" void kernel_launch(void* const* d_in, const int* in_sizes, int n_in,
                              void* d_out, int out_size, void* d_ws, size_t ws_size,
                              hipStream_t stream)
{
    Prm p;
    const float* x      = (const float*)d_in[0];
    p.eps_q  = (const float*)d_in[1];
    p.eps_p  = (const float*)d_in[2];
    const float* Wih_q  = (const float*)d_in[3];
    const float* Whh_q  = (const float*)d_in[4];
    p.bih_q  = (const float*)d_in[5];
    p.bhh_q  = (const float*)d_in[6];
    const float* Wd_q   = (const float*)d_in[7];
    p.bd_q   = (const float*)d_in[8];
    const float* Wmu_q  = (const float*)d_in[9];
    p.bmu_q  = (const float*)d_in[10];
    const float* Wsig_q = (const float*)d_in[11];
    p.bsig_q = (const float*)d_in[12];
    p.Wp     = (const float*)d_in[13];
    p.bp     = (const float*)d_in[14];
    p.up     = (const float*)d_in[15];
    p.Wlg    = (const float*)d_in[16];
    p.blg    = (const float*)d_in[17];
    const float* Wih_p  = (const float*)d_in[18];
    const float* Whh_p  = (const float*)d_in[19];
    p.bih_p  = (const float*)d_in[20];
    p.bhh_p  = (const float*)d_in[21];
    const float* Wd_p   = (const float*)d_in[22];
    p.bd_p   = (const float*)d_in[23];
    const float* Wmu_p  = (const float*)d_in[24];
    p.bmu_p  = (const float*)d_in[25];
    const float* Wsig_p = (const float*)d_in[26];
    p.bsig_p = (const float*)d_in[27];

    p.out_o  = (float*)d_out;
    p.out_mu = p.out_o + (size_t)CB * CW * COUT;
    p.out_lv = p.out_mu + (size_t)CB * CW * CZ;

    const bool BIGM = ws_size >= (size_t)400 * 1024 * 1024;
    const int NS = BIGM ? (CW + 1) : 2;
    const int NT = BIGM ? CW : 1;
    const int NZ = BIGM ? CW : 2;

    char* wp_ = (char*)d_ws;
    auto carve = [&](size_t bytes) -> void* {
        void* q = (void*)wp_;
        wp_ += (bytes + 255) & ~(size_t)255;
        return q;
    };
    p.e_f0 = (float*)carve((size_t)CB * CH * 4);
    p.e_f1 = (float*)carve((size_t)CB * CH * 4);
    p.d_f0 = (float*)carve((size_t)CB * CH * 4);
    p.d_f1 = (float*)carve((size_t)CB * CH * 4);
    p.e_h     = (bf16*)carve((size_t)NS * CB * CH * 2);
    p.d_h     = (bf16*)carve((size_t)NS * CB * CH * 2);
    p.dvec_h  = (bf16*)carve((size_t)NT * CB * CD * 2);
    p.ddvec_h = (bf16*)carve((size_t)NT * CB * CD * 2);
    p.ztmp_h  = (float*)carve((size_t)NT * CB * CZ * 4);
    p.zflow_h = (bf16*)carve((size_t)NS * CB * CZ * 2);
    p.ztlg_h  = (bf16*)carve((size_t)NZ * CB * CZ * 2);
    p.qbar    = (u32*)carve((size_t)128 * 16 * 4);
    p.pbar    = (u32*)carve((size_t)128 * 16 * 4);
    p.zbar    = (u32*)carve((size_t)128 * 16 * 4);
    p.pdone   = (u32*)carve((size_t)128 * 16 * 4);
    p.qg      = (u32*)carve((size_t)128 * 16 * 4);
    p.ql      = (u32*)carve((size_t)128 * 16 * 4);
    p.qt      = (u32*)carve((size_t)128 * 16 * 4);
    p.qf      = (u32*)carve((size_t)128 * 16 * 4);
    p.pg      = (u32*)carve((size_t)128 * 16 * 4);
    p.pl      = (u32*)carve((size_t)128 * 16 * 4);
    bf16* x_b    = (bf16*)carve((size_t)CB * CW * CIN * 2);
    bf16* Wih_qb = (bf16*)carve((size_t)3 * CH * CIN * 2);
    bf16* Whh_qb = (bf16*)carve((size_t)3 * CH * CH * 2);
    bf16* Wd_qb  = (bf16*)carve((size_t)CD * (CZ + CH) * 2);
    bf16* Wmu_qb = (bf16*)carve((size_t)CZ * CD * 2);
    bf16* Wsg_qb = (bf16*)carve((size_t)CZ * CD * 2);
    bf16* Wih_pb = (bf16*)carve((size_t)3 * CH * CZ * 2);
    bf16* Whh_pb = (bf16*)carve((size_t)3 * CH * CH * 2);
    bf16* Wd_pb  = (bf16*)carve((size_t)CD * CH * 2);
    bf16* Wmu_pb = (bf16*)carve((size_t)COUT * CD * 2);
    bf16* Wsg_pb = (bf16*)carve((size_t)COUT * CD * 2);
    p.x_b = x_b;       p.Wih_qb = Wih_qb; p.Whh_qb = Whh_qb;
    p.Wd_qb = Wd_qb;   p.Wmu_qb = Wmu_qb; p.Wsg_qb = Wsg_qb;
    p.Wih_pb = Wih_pb; p.Whh_pb = Whh_pb; p.Wd_pb = Wd_pb;
    p.Wmu_pb = Wmu_pb; p.Wsg_pb = Wsg_pb;

    hipMemsetAsync(p.e_f0, 0, (size_t)CB * CH * 4, stream);
    hipMemsetAsync(p.d_f0, 0, (size_t)CB * CH * 4, stream);
    hipMemsetAsync(p.e_h, 0, (size_t)CB * CH * 2, stream);      // slot 0
    hipMemsetAsync(p.d_h, 0, (size_t)CB * CH * 2, stream);
    hipMemsetAsync(p.zflow_h, 0, (size_t)CB * CZ * 2, stream);  // slot 0
    hipMemsetAsync(p.qbar, 0, (size_t)128 * 16 * 4 * 10, stream); // all 10 flag arrays (contiguous)

    auto cvt = [&](const float* s, bf16* d, size_t n) {
        k_cvt<<<dim3((unsigned)((n / 4 + 255) / 256)), dim3(256), 0, stream>>>(s, d, (int)n);
    };
    cvt(x,      x_b,    (size_t)CB * CW * CIN);
    cvt(Wih_q,  Wih_qb, (size_t)3 * CH * CIN);
    cvt(Whh_q,  Whh_qb, (size_t)3 * CH * CH);
    cvt(Wd_q,   Wd_qb,  (size_t)CD * (CZ + CH));
    cvt(Wmu_q,  Wmu_qb, (size_t)CZ * CD);
    cvt(Wsig_q, Wsg_qb, (size_t)CZ * CD);
    cvt(Wih_p,  Wih_pb, (size_t)3 * CH * CZ);
    cvt(Whh_p,  Whh_pb, (size_t)3 * CH * CH);
    cvt(Wd_p,   Wd_pb,  (size_t)CD * CH);
    cvt(Wmu_p,  Wmu_pb, (size_t)COUT * CD);
    cvt(Wsig_p, Wsg_pb, (size_t)COUT * CD);

    if (BIGM)
        mega<true><<<dim3(256), dim3(512), SMEM_BYTES, stream>>>(p);
    else
        mega<false><<<dim3(256), dim3(512), SMEM_BYTES, stream>>>(p);
}